// Round 6
// baseline (3385.703 us; speedup 1.0000x reference)
//
#include <hip/hip_runtime.h>
#include <stdint.h>

typedef unsigned short u16;
typedef __bf16 bf16x8 __attribute__((ext_vector_type(8)));
typedef float f32x4 __attribute__((ext_vector_type(4)));

constexpr int NB = 16384;        // batch tokens
constexpr int DM = 512;          // model dim
constexpr int NS = 4;            // streams
constexpr int FH = 2048;         // FFN hidden
constexpr int XW = NS * DM;      // 2048 concat width
constexpr float EPSL = 1e-5f;

__device__ __forceinline__ float bf2f(u16 u) { return __uint_as_float(((uint32_t)u) << 16); }
__device__ __forceinline__ u16 f2bf(float f) {
  uint32_t u = __float_as_uint(f);
  u += 0x7fffu + ((u >> 16) & 1u);
  return (u16)(u >> 16);
}
__device__ __forceinline__ void unpack8(uint4 p, float* f) {
  f[0] = __uint_as_float(p.x << 16); f[1] = __uint_as_float(p.x & 0xffff0000u);
  f[2] = __uint_as_float(p.y << 16); f[3] = __uint_as_float(p.y & 0xffff0000u);
  f[4] = __uint_as_float(p.z << 16); f[5] = __uint_as_float(p.z & 0xffff0000u);
  f[6] = __uint_as_float(p.w << 16); f[7] = __uint_as_float(p.w & 0xffff0000u);
}
__device__ __forceinline__ uint4 pack8(const float* f) {
  uint4 r;
  r.x = (uint32_t)f2bf(f[0]) | ((uint32_t)f2bf(f[1]) << 16);
  r.y = (uint32_t)f2bf(f[2]) | ((uint32_t)f2bf(f[3]) << 16);
  r.z = (uint32_t)f2bf(f[4]) | ((uint32_t)f2bf(f[5]) << 16);
  r.w = (uint32_t)f2bf(f[6]) | ((uint32_t)f2bf(f[7]) << 16);
  return r;
}
__device__ __forceinline__ void gl_lds16(const void* g, void* l) {
  __builtin_amdgcn_global_load_lds((const __attribute__((address_space(1))) void*)g,
                                   (__attribute__((address_space(3))) void*)l, 16, 0, 0);
}

// XCD-aware bijective remap of (bx,by,bz) from the flat id. gx%8==0 and
// total%8==0 required (all launches satisfy). Blocks co-resident on one XCD
// share gx/8 fixed A-slices + a sliding B window -> staging hits that XCD's L2.
__device__ __forceinline__ void remap(int& bx, int& by, int& bz) {
  const int gx = gridDim.x, gy = gridDim.y;
  const int fl = (blockIdx.z * gy + blockIdx.y) * gx + blockIdx.x;
  const int xcd = fl & 7;
  const int t = fl >> 3;
  const int bw = gx >> 3;
  bx = xcd * bw + t % bw;
  const int u = t / bw;
  by = u % gy;
  bz = u / gy;
}

// ---- 256-row GEMM core, frag-major LDS, 3-buffer counted-vmcnt pipeline ----
// WN = waves in N: 4 -> 256x256 tile, 512 thr; 2 -> 256x128 tile, 256 thr.
// Per wave: 128 rows x 64 cols = 8 A-frags x 4 B-frags, 32 MFMA per K-32.
// LDS layout is FRAG-MAJOR: fragment f's 64 lanes stored contiguously
// (1 KB bursts) -> ds_read_b128 is wave-contiguous (zero bank conflicts) and
// matches global_load_lds' linear dest. Global src supplies lane content
// A[frag_row + (tid&15)][k + ((tid>>4)&3)*8 ..+8] (16 rows x 64B -> coalesced).
template<int WN>
__device__ __forceinline__ void gcore(
    const u16* __restrict__ A, int lda,
    const u16* __restrict__ Bt, int K,     // Bt row stride == K
    u16* As, u16* Bs, f32x4 (&acc)[8][4], int bx, int by)
{
  constexpr int T   = 128 * WN;            // threads
  constexpr int ASL = 8192;                // u16 per A buf (16 KB)
  constexpr int BSL = 2048 * WN;           // u16 per B buf
  constexpr int AI  = 8 / WN;              // A stage instrs/thread/tile
  const int tid = threadIdx.x;
  const int ln  = tid & 63;
  const int w   = tid >> 6;
  const int m0 = bx * 256;
  const int n0 = by * (64 * WN);
  const u16* Ab = A  + (size_t)(m0 + w * 16 + (tid & 15)) * lda + ((tid >> 4) & 3) * 8;
  const u16* Bb = Bt + (size_t)(n0 + w * 16 + (tid & 15)) * K   + ((tid >> 4) & 3) * 8;

  auto stage = [&](int buf, int k0) {
#pragma unroll
    for (int i = 0; i < AI; ++i)
      gl_lds16(Ab + (size_t)(i * 32 * WN) * lda + k0, &As[buf * ASL + (i * T + tid) * 8]);
#pragma unroll
    for (int i = 0; i < 2; ++i)
      gl_lds16(Bb + (size_t)(i * 32 * WN) * K + k0, &Bs[buf * BSL + (i * T + tid) * 8]);
  };
  auto wsteady = [] {
    if constexpr (WN == 4) asm volatile("s_waitcnt vmcnt(4)" ::: "memory");
    else                   asm volatile("s_waitcnt vmcnt(6)" ::: "memory");
  };

  __syncthreads();
  const int nt = K >> 5;
  stage(0, 0);
  if (nt > 1) { stage(1, 32); wsteady(); }
  else asm volatile("s_waitcnt vmcnt(0)" ::: "memory");
  __builtin_amdgcn_s_barrier();
  asm volatile("" ::: "memory");

  const int abase = (w >> (WN == 4 ? 2 : 1)) * (8 * 512) + ln * 8;
  const int bbase = (w & (WN - 1)) * (4 * 512) + ln * 8;
  int cur = 0, nxt2 = 2;
  for (int t = 0; t < nt; ++t) {
    if (t + 2 < nt) stage(nxt2, (t + 2) * 32);   // buffer freed by prev barrier
    bf16x8 af[8], bfv[4];
#pragma unroll
    for (int mf = 0; mf < 8; ++mf) af[mf] = *(const bf16x8*)&As[cur * ASL + abase + mf * 512];
#pragma unroll
    for (int nf = 0; nf < 4; ++nf) bfv[nf] = *(const bf16x8*)&Bs[cur * BSL + bbase + nf * 512];
    __builtin_amdgcn_s_setprio(1);
#pragma unroll
    for (int mf = 0; mf < 8; ++mf)
#pragma unroll
      for (int nf = 0; nf < 4; ++nf)
        acc[mf][nf] = __builtin_amdgcn_mfma_f32_16x16x32_bf16(af[mf], bfv[nf], acc[mf][nf], 0, 0, 0);
    __builtin_amdgcn_s_setprio(0);
    if (t + 2 < nt)      wsteady();              // t+1 landed, t+2 in flight
    else if (t + 1 < nt) asm volatile("s_waitcnt vmcnt(0)" ::: "memory");
    __builtin_amdgcn_s_barrier();
    asm volatile("" ::: "memory");
    cur = cur + 1;  if (cur == 3)  cur = 0;
    nxt2 = nxt2 + 1; if (nxt2 == 3) nxt2 = 0;
  }
  asm volatile("" ::: "memory");
}

// generic GEMM with per-z offsets: C = A*Bt^T + bias [+Rsd][ReLU]
template<bool RELU, bool RESID, bool OUTF32, int WN>
__global__ __launch_bounds__(128 * WN, 2) void k_gemm(
    const u16* __restrict__ A, int lda, long aZ,
    const u16* __restrict__ Bt, long bZ,
    const float* __restrict__ bias, long biasZ,
    const u16* __restrict__ Rsd, int ldr, long rZ,
    void* __restrict__ Cp, int ldc, long cZ, int K)
{
  int bx, by, bz; remap(bx, by, bz);
  A += (long)bz * aZ; Bt += (long)bz * bZ; bias += (long)bz * biasZ;
  __shared__ alignas(16) u16 As[3 * 8192];
  __shared__ alignas(16) u16 Bs[3 * 2048 * WN];
  f32x4 acc[8][4] = {};
  gcore<WN>(A, lda, Bt, K, As, Bs, acc, bx, by);
  const int ln = threadIdx.x & 63;
  const int w = threadIdx.x >> 6;
  const int wm = w >> (WN == 4 ? 2 : 1), wn = w & (WN - 1);
  const int m0 = bx * 256, n0 = by * (64 * WN);
#pragma unroll
  for (int nf = 0; nf < 4; ++nf) {
    const int gc = n0 + wn * 64 + nf * 16 + (ln & 15);
    const float bv = bias[gc];
#pragma unroll
    for (int mf = 0; mf < 8; ++mf) {
#pragma unroll
      for (int j = 0; j < 4; ++j) {
        const int gr = m0 + wm * 128 + mf * 16 + (ln >> 4) * 4 + j;
        float v = acc[mf][nf][j] + bv;
        if constexpr (RESID) v += bf2f(Rsd[(long)bz * rZ + (size_t)gr * ldr + gc]);
        if constexpr (RELU)  v = v > 0.f ? v : 0.f;
        if constexpr (OUTF32) ((float*)Cp)[(long)bz * cZ + (size_t)gr * ldc + gc] = v;
        else                  ((u16*)Cp)[(long)bz * cZ + (size_t)gr * ldc + gc] = f2bf(v);
      }
    }
  }
}

// K-projection + fused q.k dot. z = s*4+kp; wave wn covers exactly one head.
// Writes raw scores (x1/8) to wbuf[s][b][h][kp]. K-bias softmax-invariant, dropped.
__global__ __launch_bounds__(512, 2) void k_kdot(
    const u16* __restrict__ xcat, const u16* __restrict__ WkT_l,
    const u16* __restrict__ Qb, float* __restrict__ wbuf)
{
  int bx, by, bz; remap(bx, by, bz);
  const int s = bz >> 2, kp = bz & 3;
  __shared__ alignas(16) u16 As[3 * 8192];
  __shared__ alignas(16) u16 Bs[3 * 8192];
  f32x4 acc[8][4] = {};
  gcore<4>(xcat + kp * DM, XW, WkT_l + (size_t)s * DM * DM, DM, As, Bs, acc, bx, by);
  const int ln = threadIdx.x & 63;
  const int w = threadIdx.x >> 6;
  const int wm = w >> 2, wn = w & 3;
  const int m0 = bx * 256, n0 = by * 256;
  const int h = (n0 >> 6) + wn;
  float p[8][4];
#pragma unroll
  for (int mf = 0; mf < 8; ++mf)
#pragma unroll
    for (int j = 0; j < 4; ++j) p[mf][j] = 0.f;
#pragma unroll
  for (int nf = 0; nf < 4; ++nf) {
    const int gc = n0 + wn * 64 + nf * 16 + (ln & 15);
#pragma unroll
    for (int mf = 0; mf < 8; ++mf) {
#pragma unroll
      for (int j = 0; j < 4; ++j) {
        const int gr = m0 + wm * 128 + mf * 16 + (ln >> 4) * 4 + j;
        p[mf][j] += acc[mf][nf][j] * bf2f(Qb[((size_t)s * NB + gr) * DM + gc]);
      }
    }
  }
#pragma unroll
  for (int mf = 0; mf < 8; ++mf)
#pragma unroll
    for (int j = 0; j < 4; ++j) {
      float v = p[mf][j];
      v += __shfl_xor(v, 1, 64);
      v += __shfl_xor(v, 2, 64);
      v += __shfl_xor(v, 4, 64);
      v += __shfl_xor(v, 8, 64);
      p[mf][j] = v;
    }
  if ((ln & 15) == 0) {
#pragma unroll
    for (int mf = 0; mf < 8; ++mf)
#pragma unroll
      for (int j = 0; j < 4; ++j) {
        const int gr = m0 + wm * 128 + mf * 16 + (ln >> 4) * 4 + j;
        wbuf[(((size_t)s * NB + gr) * 8 + h) * 4 + kp] = p[mf][j] * 0.125f;
      }
  }
}

// V-projection for one key position (N=2048 over streams), softmax-weighted,
// chained over kp via bf16 RMW into ctxc [B][2048].
template<bool FIRST>
__global__ __launch_bounds__(512, 2) void k_gemmv(
    const u16* __restrict__ xcat, const u16* __restrict__ WvT_l,
    const float* __restrict__ bv_l, const float* __restrict__ wbuf, int kp,
    u16* __restrict__ ctxc)
{
  int bx, by, bz; remap(bx, by, bz); (void)bz;
  __shared__ alignas(16) u16 As[3 * 8192];
  __shared__ alignas(16) u16 Bs[3 * 8192];
  f32x4 acc[8][4] = {};
  gcore<4>(xcat + kp * DM, XW, WvT_l, DM, As, Bs, acc, bx, by);
  const int ln = threadIdx.x & 63;
  const int w = threadIdx.x >> 6;
  const int wm = w >> 2, wn = w & 3;
  const int m0 = bx * 256, n0 = by * 256;
  const int s  = n0 >> 9;
  const int hh = ((n0 >> 6) + wn) & 7;
  float wv[8][4];
#pragma unroll
  for (int mf = 0; mf < 8; ++mf)
#pragma unroll
    for (int j = 0; j < 4; ++j) {
      const int gr = m0 + wm * 128 + mf * 16 + (ln >> 4) * 4 + j;
      wv[mf][j] = wbuf[(((size_t)s * NB + gr) * 8 + hh) * 4 + kp];
    }
#pragma unroll
  for (int nf = 0; nf < 4; ++nf) {
    const int gc = n0 + wn * 64 + nf * 16 + (ln & 15);
    const float bvv = bv_l[gc];
#pragma unroll
    for (int mf = 0; mf < 8; ++mf) {
#pragma unroll
      for (int j = 0; j < 4; ++j) {
        const int gr = m0 + wm * 128 + mf * 16 + (ln >> 4) * 4 + j;
        float v = (acc[mf][nf][j] + bvv) * wv[mf][j];
        if constexpr (!FIRST) v += bf2f(ctxc[(size_t)gr * XW + gc]);
        ctxc[(size_t)gr * XW + gc] = f2bf(v);
      }
    }
  }
}

// softmax over kp in-place on wbuf [S][B][H][4]; optional write to attn0 [B][S][H][4]
__global__ __launch_bounds__(256) void k_softmax(
    float* __restrict__ wbuf, float* __restrict__ a0)
{
  const int t = blockIdx.x * 256 + threadIdx.x;   // (s*NB + b)*8 + h
  float4 v = ((const float4*)wbuf)[t];
  const float mx = fmaxf(fmaxf(v.x, v.y), fmaxf(v.z, v.w));
  float4 e;
  e.x = __expf(v.x - mx); e.y = __expf(v.y - mx);
  e.z = __expf(v.z - mx); e.w = __expf(v.w - mx);
  const float inv = 1.f / (e.x + e.y + e.z + e.w);
  e.x *= inv; e.y *= inv; e.z *= inv; e.w *= inv;
  ((float4*)wbuf)[t] = e;
  if (a0 != nullptr) {
    const int s = t >> 17, b = (t >> 3) & (NB - 1), h = t & 7;
    ((float4*)a0)[((size_t)b * NS + s) * 8 + h] = e;
  }
}

// in-place LayerNorm over each 512-wide stream block of xcat; wave per (b,s)
__global__ __launch_bounds__(256) void k_ln(
    u16* __restrict__ xcat, const float* __restrict__ g, const float* __restrict__ bb)
{
  const int ln = threadIdx.x & 63;
  const int row = blockIdx.x * 4 + (threadIdx.x >> 6);
  const int b = row >> 2, s = row & 3;
  u16* p = xcat + (size_t)b * XW + s * DM;
  float v[8];
  { uint4 t = ((const uint4*)p)[ln]; unpack8(t, v); }
  float sum = 0.f;
#pragma unroll
  for (int j = 0; j < 8; ++j) sum += v[j];
#pragma unroll
  for (int off = 1; off < 64; off <<= 1) sum += __shfl_xor(sum, off, 64);
  const float mu = sum * (1.f / DM);
  float s2 = 0.f;
#pragma unroll
  for (int j = 0; j < 8; ++j) { float d = v[j] - mu; s2 += d * d; }
#pragma unroll
  for (int off = 1; off < 64; off <<= 1) s2 += __shfl_xor(s2, off, 64);
  const float rs = rsqrtf(s2 * (1.f / DM) + EPSL);
  const int e0 = s * DM + ln * 8;
  float o[8];
#pragma unroll
  for (int j = 0; j < 8; ++j) o[j] = (v[j] - mu) * rs * g[e0 + j] + bb[e0 + j];
  ((uint4*)p)[ln] = pack8(o);
}

// pack 4 fp32 streams -> xcat bf16 [B][S*D]
__global__ void k_pack(const float* __restrict__ t0, const float* __restrict__ t1,
                       const float* __restrict__ t2, const float* __restrict__ t3,
                       u16* __restrict__ xcat)
{
  const int total = NB * XW / 8;
  for (int t = blockIdx.x * blockDim.x + threadIdx.x; t < total; t += gridDim.x * blockDim.x) {
    const int b = t >> 8;
    const int r = t & 255;
    const int s = r >> 6;
    const int d0 = (r & 63) * 8;
    const float* p = (s == 0) ? t0 : (s == 1) ? t1 : (s == 2) ? t2 : t3;
    float f[8];
#pragma unroll
    for (int j = 0; j < 8; ++j) f[j] = p[(size_t)b * DM + d0 + j];
    ((uint4*)xcat)[t] = pack8(f);
  }
}

// transpose + fp32->bf16: src nb x [R][C] -> dst nb x [C][R]; pow2 dims (pass logs)
__global__ void k_tcvt(const float* __restrict__ src, u16* __restrict__ dst,
                       int rlog, int clog, int nb)
{
  const int mlog = rlog + clog;
  const size_t total = (size_t)nb << mlog;
  for (size_t t = (size_t)blockIdx.x * blockDim.x + threadIdx.x; t < total;
       t += (size_t)gridDim.x * blockDim.x) {
    const size_t mat = t >> mlog;
    const uint32_t rem = (uint32_t)(t & ((1u << mlog) - 1));
    const uint32_t n = rem >> rlog;
    const uint32_t r = rem & ((1u << rlog) - 1);
    dst[t] = f2bf(src[(mat << mlog) + ((size_t)r << clog) + n]);
  }
}

extern "C" void kernel_launch(void* const* d_in, const int* in_sizes, int n_in,
                              void* d_out, int out_size, void* d_ws, size_t ws_size,
                              hipStream_t stream)
{
  (void)in_sizes; (void)n_in; (void)out_size;
  const float* t0  = (const float*)d_in[0];
  const float* t1  = (const float*)d_in[1];
  const float* t2  = (const float*)d_in[2];
  const float* t3  = (const float*)d_in[3];
  const float* Wq  = (const float*)d_in[4];
  const float* bq  = (const float*)d_in[5];
  const float* Wk  = (const float*)d_in[6];
  const float* Wv  = (const float*)d_in[8];
  const float* bv  = (const float*)d_in[9];
  const float* Wo  = (const float*)d_in[10];
  const float* bo  = (const float*)d_in[11];
  const float* lng = (const float*)d_in[12];
  const float* lnb = (const float*)d_in[13];
  const float* W1  = (const float*)d_in[14];
  const float* b1  = (const float*)d_in[15];
  const float* W2  = (const float*)d_in[16];
  const float* b2  = (const float*)d_in[17];
  const float* Wf1 = (const float*)d_in[18];
  const float* bf1 = (const float*)d_in[19];
  const float* Wf2 = (const float*)d_in[20];
  const float* bf2 = (const float*)d_in[21];

  size_t off = 0;
  char* ws = (char*)d_ws;
  auto take = [&](size_t n) { char* p = ws + off; off += (n + 255) & ~(size_t)255; return p; };
  u16* WqT  = (u16*)take(8ull * DM * DM * 2);        //  4 MiB
  u16* WkT  = (u16*)take(8ull * DM * DM * 2);        //  4
  u16* WvT  = (u16*)take(8ull * DM * DM * 2);        //  4
  u16* WoT  = (u16*)take(8ull * DM * DM * 2);        //  4
  u16* W1T  = (u16*)take(8ull * DM * FH * 2);        // 16
  u16* W2T  = (u16*)take(8ull * FH * DM * 2);        // 16
  u16* Wf1T = (u16*)take((size_t)XW * 1024 * 2);     //  4
  u16* Wf2T = (u16*)take((size_t)1024 * DM * 2);     //  1
  u16* xcat = (u16*)take((size_t)NB * XW * 2);       // 64
  char* U1  = take((size_t)NB * XW * 2);             // 64: Qb | ctxc | ffn1 | y1
  float* wbuf = (float*)take(4ull * NB * 8 * 4 * 4); //  8
  const size_t needed = off;                          // ~189 MiB

  u16* Qb   = (u16*)U1;   // [S][B][512]
  u16* ctxc = (u16*)U1;   // [B][2048]
  u16* ffn1 = (u16*)U1;   // [B][2048] per stream
  u16* y1   = (u16*)U1;   // [B][1024]
  float* attn0 = (float*)d_out + (size_t)NB * DM;

  if (needed > ws_size) return;  // diagnostic: clean fail instead of GPU fault

  // weight prep: fp32 -> bf16, transposed to [N][K]
  k_tcvt<<<dim3(1024), dim3(256), 0, stream>>>(Wq, WqT, 9, 9, 8);
  k_tcvt<<<dim3(1024), dim3(256), 0, stream>>>(Wk, WkT, 9, 9, 8);
  k_tcvt<<<dim3(1024), dim3(256), 0, stream>>>(Wv, WvT, 9, 9, 8);
  k_tcvt<<<dim3(1024), dim3(256), 0, stream>>>(Wo, WoT, 9, 9, 8);
  k_tcvt<<<dim3(1024), dim3(256), 0, stream>>>(W1, W1T, 9, 11, 8);
  k_tcvt<<<dim3(1024), dim3(256), 0, stream>>>(W2, W2T, 11, 9, 8);
  k_tcvt<<<dim3(1024), dim3(256), 0, stream>>>(Wf1, Wf1T, 11, 10, 1);
  k_tcvt<<<dim3(1024), dim3(256), 0, stream>>>(Wf2, Wf2T, 10, 9, 1);
  k_pack<<<dim3(2048), dim3(256), 0, stream>>>(t0, t1, t2, t3, xcat);

  const size_t WSQ = (size_t)DM * DM;
  for (int ly = 0; ly < 2; ++ly) {
    const u16* WqT_l = WqT + (size_t)ly * 4 * WSQ;
    const u16* WkT_l = WkT + (size_t)ly * 4 * WSQ;
    const u16* WvT_l = WvT + (size_t)ly * 4 * WSQ;
    const u16* WoT_l = WoT + (size_t)ly * 4 * WSQ;
    // Q projection, all streams (z = s)
    k_gemm<false, false, false, 4><<<dim3(64, 2, 4), dim3(512), 0, stream>>>(
        xcat, XW, DM, WqT_l, WSQ, bq + (size_t)ly * XW, DM,
        nullptr, 0, 0, Qb, DM, (long)NB * DM, DM);
    // K projection + fused q.k dot, all (s,kp) in one launch
    k_kdot<<<dim3(64, 2, 16), dim3(512), 0, stream>>>(xcat, WkT_l, Qb, wbuf);
    k_softmax<<<dim3(4 * NB * 8 / 256), dim3(256), 0, stream>>>(
        wbuf, (ly == 0) ? attn0 : (float*)nullptr);
    // V projection, weighted, chained over kp (bf16 RMW into ctxc)
    k_gemmv<true><<<dim3(64, 8), dim3(512), 0, stream>>>(
        xcat, WvT_l, bv + (size_t)ly * XW, wbuf, 0, ctxc);
    for (int kp = 1; kp < 4; ++kp)
      k_gemmv<false><<<dim3(64, 8), dim3(512), 0, stream>>>(
          xcat, WvT_l, bv + (size_t)ly * XW, wbuf, kp, ctxc);
    // O projection, residual-fused, in-place into xcat (z = s)
    k_gemm<false, true, false, 4><<<dim3(64, 2, 4), dim3(512), 0, stream>>>(
        ctxc, XW, DM, WoT_l, WSQ, bo + (size_t)ly * XW, DM,
        xcat, XW, DM, xcat, XW, DM, DM);
    k_ln<<<dim3(NB), dim3(256), 0, stream>>>(xcat, lng + ly * XW, lnb + ly * XW);
    // FFN per stream, residual-fused, in-place into xcat
    for (int s = 0; s < NS; ++s) {
      const size_t wsl = (size_t)(ly * 4 + s);
      k_gemm<true, false, false, 4><<<dim3(64, 8, 1), dim3(512), 0, stream>>>(
          xcat + s * DM, XW, 0, W1T + wsl * (size_t)DM * FH, 0, b1 + wsl * FH, 0,
          nullptr, 0, 0, ffn1, FH, 0, DM);
      k_gemm<false, true, false, 2><<<dim3(64, 4, 1), dim3(256), 0, stream>>>(
          ffn1, FH, 0, W2T + wsl * (size_t)FH * DM, 0, b2 + wsl * DM, 0,
          xcat + s * DM, XW, 0, xcat + s * DM, XW, 0, FH);
    }
  }
  // final fusion MLP
  k_gemm<true, false, false, 4><<<dim3(64, 4, 1), dim3(512), 0, stream>>>(
      xcat, XW, 0, Wf1T, 0, bf1, 0, nullptr, 0, 0, y1, 1024, 0, XW);
  k_gemm<false, false, true, 2><<<dim3(64, 4, 1), dim3(256), 0, stream>>>(
      y1, 1024, 0, Wf2T, 0, bf2, 0, nullptr, 0, 0, d_out, DM, 0, 1024);
}